// Round 4
// baseline (379.259 us; speedup 1.0000x reference)
//
#include <hip/hip_runtime.h>
#include <hip/hip_fp16.h>
#include <stdint.h>

// ---------------------------------------------------------------------------
// GCN 3-layer + edge weights.
// v4: rank-based packed CSR (4 B/edge, atomic-free fill) +
//     fused gather->MFMA-GEMM per layer + bf16 features. Ping-pong h buffers.
// ---------------------------------------------------------------------------

#define NF 128

typedef unsigned short u16;
typedef unsigned int u32;
typedef __attribute__((ext_vector_type(8))) short short8;   // 8 bf16 = 16 B
typedef __attribute__((ext_vector_type(4))) float f32x4;

__device__ __forceinline__ float bf2f(u16 v) {
    union { unsigned u; float f; } x; x.u = (unsigned)v << 16; return x.f;
}
__device__ __forceinline__ u16 f2bf(float f) {
    union { float f; unsigned u; } x; x.f = f;
    unsigned r = (x.u + 0x7FFFu + ((x.u >> 16) & 1u)) >> 16;
    return (u16)r;
}

// ============================ CSR build ====================================

__global__ __launch_bounds__(256) void hist_rank(
    const int* __restrict__ dst, int* __restrict__ counts,
    int* __restrict__ rank, int n_edges)
{
    int e = blockIdx.x * 256 + threadIdx.x;
    if (e < n_edges) rank[e] = atomicAdd(&counts[dst[e]], 1);
}

__global__ __launch_bounds__(256) void scan_pass1(
    const int* __restrict__ counts, int* __restrict__ bsums, int n)
{
    __shared__ int s[256];
    int i = blockIdx.x * 256 + threadIdx.x;
    s[threadIdx.x] = (i < n) ? counts[i] : 0;
    __syncthreads();
    for (int off = 128; off > 0; off >>= 1) {
        if (threadIdx.x < off) s[threadIdx.x] += s[threadIdx.x + off];
        __syncthreads();
    }
    if (threadIdx.x == 0) bsums[blockIdx.x] = s[0];
}

__global__ __launch_bounds__(256) void scan_pass2(int* __restrict__ bsums, int G)
{
    __shared__ int s[256];
    int t = threadIdx.x;
    int v = (t < G) ? bsums[t] : 0;
    s[t] = v;
    __syncthreads();
    for (int off = 1; off < 256; off <<= 1) {
        int u = (t >= off) ? s[t - off] : 0;
        __syncthreads();
        s[t] += u;
        __syncthreads();
    }
    if (t < G) bsums[t] = s[t] - v;
    if (t == 0) bsums[G] = s[255];
}

__global__ __launch_bounds__(256) void scan_pass3(
    int* __restrict__ rowptr, const int* __restrict__ bsums, int n, int G)
{
    __shared__ int s[256];
    int t = threadIdx.x;
    int i = blockIdx.x * 256 + t;
    int v = (i < n) ? rowptr[i] : 0;
    s[t] = v;
    __syncthreads();
    for (int off = 1; off < 256; off <<= 1) {
        int u = (t >= off) ? s[t - off] : 0;
        __syncthreads();
        s[t] += u;
        __syncthreads();
    }
    int excl = s[t] - v + bsums[blockIdx.x];
    if (i < n) rowptr[i] = excl;
    if (i == 0) rowptr[n] = bsums[G];
}

__global__ __launch_bounds__(256) void fill_packed(
    const int* __restrict__ src, const int* __restrict__ dst,
    const float* __restrict__ ew, const int* __restrict__ rowptr,
    const int* __restrict__ rank, u32* __restrict__ ppairs, int n_edges)
{
    int e = blockIdx.x * 256 + threadIdx.x;
    if (e >= n_edges) return;
    int pos = rowptr[dst[e]] + rank[e];
    ppairs[pos] = ((u32)src[e] << 16) |
                  (u32)__half_as_ushort(__float2half_rn(ew[e]));
}

// ============================ casts ========================================

__global__ __launch_bounds__(256) void cast_x_bf16(
    const float* __restrict__ in, u16* __restrict__ out, int n_elem)
{
    int idx = (blockIdx.x * 256 + threadIdx.x) * 4;
    if (idx >= n_elem) return;
    float4 v = *reinterpret_cast<const float4*>(in + idx);
    ushort4 o;
    o.x = f2bf(v.x); o.y = f2bf(v.y); o.z = f2bf(v.z); o.w = f2bf(v.w);
    *reinterpret_cast<ushort4*>(out + idx) = o;
}

__global__ __launch_bounds__(256) void prep_weights(
    const float* __restrict__ Wr, const float* __restrict__ W1,
    const float* __restrict__ W2, const float* __restrict__ W3,
    const float* __restrict__ Wop, u16* __restrict__ Wt, u16* __restrict__ Wtop)
{
    int i = blockIdx.x * 256 + threadIdx.x;
    if (i < 4 * 16384) {
        int w = i >> 14, r = i & 16383;
        int nn = r >> 7, kk = r & 127;
        const float* W = (w == 0) ? Wr : (w == 1) ? W1 : (w == 2) ? W2 : W3;
        Wt[i] = f2bf(W[kk * NF + nn]);
    } else {
        int r = i - 4 * 16384;
        if (r < 48 * 128) {
            int nn = r >> 7, kk = r & 127;
            Wtop[r] = (nn < 40) ? f2bf(Wop[kk * 40 + nn]) : (u16)0;
        }
    }
}

// ==================== fused gather + MFMA GEMM layer =======================
template<int RELU, int RES>
__global__ __launch_bounds__(256) void layer_fused(
    const u16* __restrict__ X, const int* __restrict__ rowptr,
    const u32* __restrict__ ppairs, const u16* __restrict__ Wt,
    const float* __restrict__ bias, const u16* __restrict__ resid,
    u16* __restrict__ out, int nrows)
{
    __shared__ u16 Bs[128 * 128];   // 32 KB weights, granule-XOR swizzled
    __shared__ u16 As[64 * 128];    // 16 KB gathered A-tile, swizzled
    const int tid = threadIdx.x;

    #pragma unroll
    for (int i = 0; i < 8; i++) {
        int G = tid + i * 256;
        int row = G >> 4, g = G & 15, gs = g ^ (row & 7);
        *reinterpret_cast<short8*>(&Bs[row * NF + gs * 8]) =
            *reinterpret_cast<const short8*>(Wt + (size_t)G * 8);
    }

    const int row0 = blockIdx.x * 64;
    const int fl = tid & 15;
    const int ng = tid >> 4;
    for (int b = 0; b < 4; b++) {
        int nl = b * 16 + ng;
        int node = row0 + nl;
        float acc[8];
        #pragma unroll
        for (int j = 0; j < 8; j++) acc[j] = 0.f;
        if (node < nrows) {
            int e0 = rowptr[node], e1 = rowptr[node + 1];
            for (int e = e0; e < e1; ++e) {
                u32 p = ppairs[e];
                float w = __half2float(__ushort_as_half((u16)(p & 0xFFFFu)));
                int s = p >> 16;
                short8 v = *reinterpret_cast<const short8*>(
                    X + (size_t)s * NF + fl * 8);
                #pragma unroll
                for (int j = 0; j < 8; j++)
                    acc[j] = fmaf(bf2f((u16)v[j]), w, acc[j]);
            }
        }
        short8 o;
        #pragma unroll
        for (int j = 0; j < 8; j++) o[j] = (short)f2bf(acc[j]);
        int gs = fl ^ (nl & 7);
        *reinterpret_cast<short8*>(&As[nl * NF + gs * 8]) = o;
    }
    __syncthreads();

    const int wave = tid >> 6, lane = tid & 63;
    const int lrow = lane & 15, lk = lane >> 4;
    const int rloc = wave * 16 + lrow;

    short8 a[4];
    #pragma unroll
    for (int t = 0; t < 4; t++) {
        int g = t * 4 + lk, gs = g ^ (rloc & 7);
        a[t] = *reinterpret_cast<const short8*>(&As[rloc * NF + gs * 8]);
    }

    f32x4 acc[8];
    #pragma unroll
    for (int c = 0; c < 8; c++) { acc[c][0]=0.f; acc[c][1]=0.f; acc[c][2]=0.f; acc[c][3]=0.f; }

    #pragma unroll
    for (int t = 0; t < 4; t++) {
        #pragma unroll
        for (int c = 0; c < 8; c++) {
            int col = c * 16 + lrow;
            int g = t * 4 + lk, gs = g ^ (col & 7);
            short8 bfr = *reinterpret_cast<const short8*>(&Bs[col * NF + gs * 8]);
            acc[c] = __builtin_amdgcn_mfma_f32_16x16x32_bf16(a[t], bfr, acc[c], 0, 0, 0);
        }
    }

    const int wrow0 = row0 + wave * 16;
    #pragma unroll
    for (int c = 0; c < 8; c++) {
        int col = c * 16 + lrow;
        float bv = bias[col];
        #pragma unroll
        for (int r = 0; r < 4; r++) {
            int orow = wrow0 + lk * 4 + r;
            if (orow < nrows) {
                float v = acc[c][r] + bv;
                if (RES) v += bf2f(resid[(size_t)orow * NF + col]);
                if (RELU) v = fmaxf(v, 0.f);
                out[(size_t)orow * NF + col] = f2bf(v);
            }
        }
    }
}

// ==================== plain MFMA GEMM (residual path) ======================
template<int RELU, int RES>
__global__ __launch_bounds__(256) void gemm_mfma128(
    const u16* __restrict__ A, const u16* __restrict__ Wt,
    const float* __restrict__ bias, const u16* __restrict__ resid,
    u16* __restrict__ out, int nrows)
{
    __shared__ u16 Bs[128 * 128];
    const int tid = threadIdx.x;
    #pragma unroll
    for (int i = 0; i < 8; i++) {
        int G = tid + i * 256;
        int row = G >> 4, g = G & 15, gs = g ^ (row & 7);
        *reinterpret_cast<short8*>(&Bs[row * NF + gs * 8]) =
            *reinterpret_cast<const short8*>(Wt + (size_t)G * 8);
    }

    const int wave = tid >> 6, lane = tid & 63;
    const int lrow = lane & 15, lk = lane >> 4;
    const int row0 = blockIdx.x * 64 + wave * 16;
    const int grow = row0 + lrow;

    short8 a[4];
    if (grow < nrows) {
        const u16* Ar = A + (size_t)grow * NF + lk * 8;
        #pragma unroll
        for (int t = 0; t < 4; t++)
            a[t] = *reinterpret_cast<const short8*>(Ar + t * 32);
    } else {
        #pragma unroll
        for (int t = 0; t < 4; t++)
            #pragma unroll
            for (int j = 0; j < 8; j++) a[t][j] = 0;
    }
    __syncthreads();

    f32x4 acc[8];
    #pragma unroll
    for (int c = 0; c < 8; c++) { acc[c][0]=0.f; acc[c][1]=0.f; acc[c][2]=0.f; acc[c][3]=0.f; }

    #pragma unroll
    for (int t = 0; t < 4; t++) {
        #pragma unroll
        for (int c = 0; c < 8; c++) {
            int col = c * 16 + lrow;
            int g = t * 4 + lk, gs = g ^ (col & 7);
            short8 b = *reinterpret_cast<const short8*>(&Bs[col * NF + gs * 8]);
            acc[c] = __builtin_amdgcn_mfma_f32_16x16x32_bf16(a[t], b, acc[c], 0, 0, 0);
        }
    }

    #pragma unroll
    for (int c = 0; c < 8; c++) {
        int col = c * 16 + lrow;
        float bv = bias[col];
        #pragma unroll
        for (int r = 0; r < 4; r++) {
            int orow = row0 + lk * 4 + r;
            if (orow < nrows) {
                float v = acc[c][r] + bv;
                if (RES) v += bf2f(resid[(size_t)orow * NF + col]);
                if (RELU) v = fmaxf(v, 0.f);
                out[(size_t)orow * NF + col] = f2bf(v);
            }
        }
    }
}

__global__ __launch_bounds__(256) void gemm_out40_mfma(
    const u16* __restrict__ H, const u16* __restrict__ Wtop,
    const float* __restrict__ bop, float* __restrict__ out, int nrows)
{
    __shared__ u16 Bs[48 * 128];
    const int tid = threadIdx.x;
    #pragma unroll
    for (int i = 0; i < 3; i++) {
        int G = tid + i * 256;
        int row = G >> 4, g = G & 15, gs = g ^ (row & 7);
        *reinterpret_cast<short8*>(&Bs[row * NF + gs * 8]) =
            *reinterpret_cast<const short8*>(Wtop + (size_t)G * 8);
    }

    const int wave = tid >> 6, lane = tid & 63;
    const int lrow = lane & 15, lk = lane >> 4;
    const int row0 = blockIdx.x * 64 + wave * 16;
    const int grow = row0 + lrow;

    short8 a[4];
    if (grow < nrows) {
        const u16* Hr = H + (size_t)grow * NF + lk * 8;
        #pragma unroll
        for (int t = 0; t < 4; t++)
            a[t] = *reinterpret_cast<const short8*>(Hr + t * 32);
    } else {
        #pragma unroll
        for (int t = 0; t < 4; t++)
            #pragma unroll
            for (int j = 0; j < 8; j++) a[t][j] = 0;
    }
    __syncthreads();

    f32x4 acc[3];
    #pragma unroll
    for (int c = 0; c < 3; c++) { acc[c][0]=0.f; acc[c][1]=0.f; acc[c][2]=0.f; acc[c][3]=0.f; }

    #pragma unroll
    for (int t = 0; t < 4; t++) {
        #pragma unroll
        for (int c = 0; c < 3; c++) {
            int col = c * 16 + lrow;
            int g = t * 4 + lk, gs = g ^ (col & 7);
            short8 b = *reinterpret_cast<const short8*>(&Bs[col * NF + gs * 8]);
            acc[c] = __builtin_amdgcn_mfma_f32_16x16x32_bf16(a[t], b, acc[c], 0, 0, 0);
        }
    }

    #pragma unroll
    for (int c = 0; c < 3; c++) {
        int col = c * 16 + lrow;
        if (col < 40) {
            float bv = bop[col];
            #pragma unroll
            for (int r = 0; r < 4; r++) {
                int orow = row0 + lk * 4 + r;
                if (orow < nrows)
                    out[(size_t)orow * 40 + col] = acc[c][r] + bv;
            }
        }
    }
}

// ============================== launch =====================================

extern "C" void kernel_launch(void* const* d_in, const int* in_sizes, int n_in,
                              void* d_out, int out_size, void* d_ws, size_t ws_size,
                              hipStream_t stream)
{
    const float* x   = (const float*)d_in[0];
    const int*   src = (const int*)d_in[1];
    const int*   dst = (const int*)d_in[2];
    const float* ew  = (const float*)d_in[3];
    const float* Wr  = (const float*)d_in[4];
    const float* br  = (const float*)d_in[5];
    const float* W1  = (const float*)d_in[6];
    const float* b1  = (const float*)d_in[7];
    const float* W2  = (const float*)d_in[8];
    const float* b2  = (const float*)d_in[9];
    const float* W3  = (const float*)d_in[10];
    const float* b3  = (const float*)d_in[11];
    const float* Wop = (const float*)d_in[12];
    const float* bop = (const float*)d_in[13];
    float* out = (float*)d_out;

    const int n_nodes = in_sizes[0] / NF;   // 50000
    const int n_edges = in_sizes[1];        // 640000
    const size_t feat = (size_t)n_nodes * NF;

    // workspace layout (ping-pong h buffers to avoid RAW race in fused layers)
    u16* xb   = (u16*)d_ws;
    u16* h1b  = xb + feat;
    u16* h2b  = h1b + feat;
    u16* resb = h2b + feat;
    u16* Wt   = resb + feat;                 // 4 * 128*128
    u16* Wtop = Wt + 4 * 16384;              // 48*128
    int* rowptr = (int*)(Wtop + 48 * 128);   // n+1
    const int G1 = (n_nodes + 255) / 256;
    int* bsums  = rowptr + (n_nodes + 1);    // G1+1
    int* rank   = bsums + (G1 + 1);          // n_edges
    u32* ppairs = (u32*)(rank + n_edges);    // n_edges

    const int edge_grid = (n_edges + 255) / 256;
    const int gemm_grid = (n_nodes + 63) / 64;
    const int castx_grid = ((int)feat / 4 + 255) / 256;

    // ---- CSR build (rank-based, packed) ----
    hipMemsetAsync(rowptr, 0, (size_t)(n_nodes + 1) * sizeof(int), stream);
    hist_rank<<<edge_grid, 256, 0, stream>>>(dst, rowptr, rank, n_edges);
    scan_pass1<<<G1, 256, 0, stream>>>(rowptr, bsums, n_nodes);
    scan_pass2<<<1, 256, 0, stream>>>(bsums, G1);
    scan_pass3<<<G1, 256, 0, stream>>>(rowptr, bsums, n_nodes, G1);
    fill_packed<<<edge_grid, 256, 0, stream>>>(src, dst, ew, rowptr, rank, ppairs, n_edges);

    // ---- casts ----
    cast_x_bf16<<<castx_grid, 256, 0, stream>>>(x, xb, (int)feat);
    prep_weights<<<(4 * 16384 + 48 * 128 + 255) / 256, 256, 0, stream>>>(
        Wr, W1, W2, W3, Wop, Wt, Wtop);

    // ---- res = x @ Wr + br ----
    gemm_mfma128<0, 0><<<gemm_grid, 256, 0, stream>>>(xb, Wt, br, nullptr, resb, n_nodes);

    // ---- 3 fused GCN layers (ping-pong) ----
    layer_fused<1, 0><<<gemm_grid, 256, 0, stream>>>(
        xb, rowptr, ppairs, Wt + 16384, b1, nullptr, h1b, n_nodes);
    layer_fused<1, 0><<<gemm_grid, 256, 0, stream>>>(
        h1b, rowptr, ppairs, Wt + 2 * 16384, b2, nullptr, h2b, n_nodes);
    layer_fused<1, 1><<<gemm_grid, 256, 0, stream>>>(
        h2b, rowptr, ppairs, Wt + 3 * 16384, b3, resb, h1b, n_nodes);

    // ---- output projection ----
    gemm_out40_mfma<<<gemm_grid, 256, 0, stream>>>(h1b, Wtop, bop, out, n_nodes);
}

// Round 5
// 198.495 us; speedup vs baseline: 1.9107x; 1.9107x over previous
//
#include <hip/hip_runtime.h>
#include <hip/hip_fp16.h>
#include <stdint.h>

// ---------------------------------------------------------------------------
// GCN 3-layer + edge weights.
// v5: round-3 structure (separate gather + MFMA GEMM; gather needs max
//     occupancy, fusion starved it) + rank-based packed CSR (4 B/edge,
//     atomic-free fill) + 4-deep pipelined gather.
// ---------------------------------------------------------------------------

#define NF 128

typedef unsigned short u16;
typedef unsigned int u32;
typedef __attribute__((ext_vector_type(8))) short short8;   // 8 bf16 = 16 B
typedef __attribute__((ext_vector_type(4))) float f32x4;

__device__ __forceinline__ float bf2f(u16 v) {
    union { unsigned u; float f; } x; x.u = (unsigned)v << 16; return x.f;
}
__device__ __forceinline__ u16 f2bf(float f) {
    union { float f; unsigned u; } x; x.f = f;
    unsigned r = (x.u + 0x7FFFu + ((x.u >> 16) & 1u)) >> 16;
    return (u16)r;
}

// ============================ CSR build ====================================

__global__ __launch_bounds__(256) void hist_rank(
    const int* __restrict__ dst, int* __restrict__ counts,
    int* __restrict__ rank, int n_edges)
{
    int e = blockIdx.x * 256 + threadIdx.x;
    if (e < n_edges) rank[e] = atomicAdd(&counts[dst[e]], 1);
}

__global__ __launch_bounds__(256) void scan_pass1(
    const int* __restrict__ counts, int* __restrict__ bsums, int n)
{
    __shared__ int s[256];
    int i = blockIdx.x * 256 + threadIdx.x;
    s[threadIdx.x] = (i < n) ? counts[i] : 0;
    __syncthreads();
    for (int off = 128; off > 0; off >>= 1) {
        if (threadIdx.x < off) s[threadIdx.x] += s[threadIdx.x + off];
        __syncthreads();
    }
    if (threadIdx.x == 0) bsums[blockIdx.x] = s[0];
}

__global__ __launch_bounds__(256) void scan_pass2(int* __restrict__ bsums, int G)
{
    __shared__ int s[256];
    int t = threadIdx.x;
    int v = (t < G) ? bsums[t] : 0;
    s[t] = v;
    __syncthreads();
    for (int off = 1; off < 256; off <<= 1) {
        int u = (t >= off) ? s[t - off] : 0;
        __syncthreads();
        s[t] += u;
        __syncthreads();
    }
    if (t < G) bsums[t] = s[t] - v;
    if (t == 0) bsums[G] = s[255];
}

__global__ __launch_bounds__(256) void scan_pass3(
    int* __restrict__ rowptr, const int* __restrict__ bsums, int n, int G)
{
    __shared__ int s[256];
    int t = threadIdx.x;
    int i = blockIdx.x * 256 + t;
    int v = (i < n) ? rowptr[i] : 0;
    s[t] = v;
    __syncthreads();
    for (int off = 1; off < 256; off <<= 1) {
        int u = (t >= off) ? s[t - off] : 0;
        __syncthreads();
        s[t] += u;
        __syncthreads();
    }
    int excl = s[t] - v + bsums[blockIdx.x];
    if (i < n) rowptr[i] = excl;
    if (i == 0) rowptr[n] = bsums[G];
}

// atomic-free fill: pos = rowptr[dst] + rank; payload (src<<16)|fp16(w)
__global__ __launch_bounds__(256) void fill_packed(
    const int* __restrict__ src, const int* __restrict__ dst,
    const float* __restrict__ ew, const int* __restrict__ rowptr,
    const int* __restrict__ rank, u32* __restrict__ ppairs, int n_edges)
{
    int e = blockIdx.x * 256 + threadIdx.x;
    if (e >= n_edges) return;
    int pos = rowptr[dst[e]] + rank[e];
    ppairs[pos] = ((u32)src[e] << 16) |
                  (u32)__half_as_ushort(__float2half_rn(ew[e]));
}

// ============================ casts ========================================

__global__ __launch_bounds__(256) void cast_x_bf16(
    const float* __restrict__ in, u16* __restrict__ out, int n_elem)
{
    int idx = (blockIdx.x * 256 + threadIdx.x) * 4;
    if (idx >= n_elem) return;
    float4 v = *reinterpret_cast<const float4*>(in + idx);
    ushort4 o;
    o.x = f2bf(v.x); o.y = f2bf(v.y); o.z = f2bf(v.z); o.w = f2bf(v.w);
    *reinterpret_cast<ushort4*>(out + idx) = o;
}

__global__ __launch_bounds__(256) void prep_weights(
    const float* __restrict__ Wr, const float* __restrict__ W1,
    const float* __restrict__ W2, const float* __restrict__ W3,
    const float* __restrict__ Wop, u16* __restrict__ Wt, u16* __restrict__ Wtop)
{
    int i = blockIdx.x * 256 + threadIdx.x;
    if (i < 4 * 16384) {
        int w = i >> 14, r = i & 16383;
        int nn = r >> 7, kk = r & 127;
        const float* W = (w == 0) ? Wr : (w == 1) ? W1 : (w == 2) ? W2 : W3;
        Wt[i] = f2bf(W[kk * NF + nn]);
    } else {
        int r = i - 4 * 16384;
        if (r < 48 * 128) {
            int nn = r >> 7, kk = r & 127;
            Wtop[r] = (nn < 40) ? f2bf(Wop[kk * 40 + nn]) : (u16)0;
        }
    }
}

// ======================= gather aggregation (bf16) =========================
// 16 lanes per node, 8 features (16 B) per lane. 4-deep edge pipeline:
// 4 independent ppairs->X-row load chains per iteration for MLP.
__global__ __launch_bounds__(256) void agg_gather_b(
    const u16* __restrict__ xb, const int* __restrict__ rowptr,
    const u32* __restrict__ ppairs, u16* __restrict__ aggb, int n_nodes)
{
    int gid = blockIdx.x * 256 + threadIdx.x;
    int node = gid >> 4;
    if (node >= n_nodes) return;
    int f = (gid & 15) << 3;
    int e0 = rowptr[node];
    int e1 = rowptr[node + 1];
    float acc[8];
    #pragma unroll
    for (int j = 0; j < 8; j++) acc[j] = 0.f;

    int e = e0;
    for (; e + 4 <= e1; e += 4) {
        u32 p0 = ppairs[e + 0];
        u32 p1 = ppairs[e + 1];
        u32 p2 = ppairs[e + 2];
        u32 p3 = ppairs[e + 3];
        short8 v0 = *reinterpret_cast<const short8*>(xb + (size_t)(p0 >> 16) * NF + f);
        short8 v1 = *reinterpret_cast<const short8*>(xb + (size_t)(p1 >> 16) * NF + f);
        short8 v2 = *reinterpret_cast<const short8*>(xb + (size_t)(p2 >> 16) * NF + f);
        short8 v3 = *reinterpret_cast<const short8*>(xb + (size_t)(p3 >> 16) * NF + f);
        float w0 = __half2float(__ushort_as_half((u16)(p0 & 0xFFFFu)));
        float w1 = __half2float(__ushort_as_half((u16)(p1 & 0xFFFFu)));
        float w2 = __half2float(__ushort_as_half((u16)(p2 & 0xFFFFu)));
        float w3 = __half2float(__ushort_as_half((u16)(p3 & 0xFFFFu)));
        #pragma unroll
        for (int j = 0; j < 8; j++) {
            acc[j] = fmaf(bf2f((u16)v0[j]), w0, acc[j]);
            acc[j] = fmaf(bf2f((u16)v1[j]), w1, acc[j]);
            acc[j] = fmaf(bf2f((u16)v2[j]), w2, acc[j]);
            acc[j] = fmaf(bf2f((u16)v3[j]), w3, acc[j]);
        }
    }
    for (; e < e1; ++e) {
        u32 p = ppairs[e];
        float w = __half2float(__ushort_as_half((u16)(p & 0xFFFFu)));
        short8 v = *reinterpret_cast<const short8*>(xb + (size_t)(p >> 16) * NF + f);
        #pragma unroll
        for (int j = 0; j < 8; j++)
            acc[j] = fmaf(bf2f((u16)v[j]), w, acc[j]);
    }

    short8 o;
    #pragma unroll
    for (int j = 0; j < 8; j++) o[j] = (short)f2bf(acc[j]);
    *reinterpret_cast<short8*>(aggb + (size_t)node * NF + f) = o;
}

// ========================= MFMA GEMMs (bf16) ===============================
template<int RELU, int RES>
__global__ __launch_bounds__(256) void gemm_mfma128(
    const u16* __restrict__ A, const u16* __restrict__ Wt,
    const float* __restrict__ bias, const u16* __restrict__ resid,
    u16* __restrict__ out, int nrows)
{
    __shared__ u16 Bs[128 * 128];   // 32 KB, granule-XOR swizzled
    const int tid = threadIdx.x;
    #pragma unroll
    for (int i = 0; i < 8; i++) {
        int G = tid + i * 256;
        int row = G >> 4, g = G & 15, gs = g ^ (row & 7);
        *reinterpret_cast<short8*>(&Bs[row * NF + gs * 8]) =
            *reinterpret_cast<const short8*>(Wt + (size_t)G * 8);
    }

    const int wave = tid >> 6, lane = tid & 63;
    const int lrow = lane & 15, lk = lane >> 4;
    const int row0 = blockIdx.x * 64 + wave * 16;
    const int grow = row0 + lrow;

    short8 a[4];
    if (grow < nrows) {
        const u16* Ar = A + (size_t)grow * NF + lk * 8;
        #pragma unroll
        for (int t = 0; t < 4; t++)
            a[t] = *reinterpret_cast<const short8*>(Ar + t * 32);
    } else {
        #pragma unroll
        for (int t = 0; t < 4; t++)
            #pragma unroll
            for (int j = 0; j < 8; j++) a[t][j] = 0;
    }
    __syncthreads();

    f32x4 acc[8];
    #pragma unroll
    for (int c = 0; c < 8; c++) { acc[c][0]=0.f; acc[c][1]=0.f; acc[c][2]=0.f; acc[c][3]=0.f; }

    #pragma unroll
    for (int t = 0; t < 4; t++) {
        #pragma unroll
        for (int c = 0; c < 8; c++) {
            int col = c * 16 + lrow;
            int g = t * 4 + lk, gs = g ^ (col & 7);
            short8 b = *reinterpret_cast<const short8*>(&Bs[col * NF + gs * 8]);
            acc[c] = __builtin_amdgcn_mfma_f32_16x16x32_bf16(a[t], b, acc[c], 0, 0, 0);
        }
    }

    #pragma unroll
    for (int c = 0; c < 8; c++) {
        int col = c * 16 + lrow;
        float bv = bias[col];
        #pragma unroll
        for (int r = 0; r < 4; r++) {
            int orow = row0 + lk * 4 + r;
            if (orow < nrows) {
                float v = acc[c][r] + bv;
                if (RES) v += bf2f(resid[(size_t)orow * NF + col]);
                if (RELU) v = fmaxf(v, 0.f);
                out[(size_t)orow * NF + col] = f2bf(v);
            }
        }
    }
}

__global__ __launch_bounds__(256) void gemm_out40_mfma(
    const u16* __restrict__ H, const u16* __restrict__ Wtop,
    const float* __restrict__ bop, float* __restrict__ out, int nrows)
{
    __shared__ u16 Bs[48 * 128];
    const int tid = threadIdx.x;
    #pragma unroll
    for (int i = 0; i < 3; i++) {
        int G = tid + i * 256;
        int row = G >> 4, g = G & 15, gs = g ^ (row & 7);
        *reinterpret_cast<short8*>(&Bs[row * NF + gs * 8]) =
            *reinterpret_cast<const short8*>(Wtop + (size_t)G * 8);
    }

    const int wave = tid >> 6, lane = tid & 63;
    const int lrow = lane & 15, lk = lane >> 4;
    const int row0 = blockIdx.x * 64 + wave * 16;
    const int grow = row0 + lrow;

    short8 a[4];
    if (grow < nrows) {
        const u16* Hr = H + (size_t)grow * NF + lk * 8;
        #pragma unroll
        for (int t = 0; t < 4; t++)
            a[t] = *reinterpret_cast<const short8*>(Hr + t * 32);
    } else {
        #pragma unroll
        for (int t = 0; t < 4; t++)
            #pragma unroll
            for (int j = 0; j < 8; j++) a[t][j] = 0;
    }
    __syncthreads();

    f32x4 acc[3];
    #pragma unroll
    for (int c = 0; c < 3; c++) { acc[c][0]=0.f; acc[c][1]=0.f; acc[c][2]=0.f; acc[c][3]=0.f; }

    #pragma unroll
    for (int t = 0; t < 4; t++) {
        #pragma unroll
        for (int c = 0; c < 3; c++) {
            int col = c * 16 + lrow;
            int g = t * 4 + lk, gs = g ^ (col & 7);
            short8 b = *reinterpret_cast<const short8*>(&Bs[col * NF + gs * 8]);
            acc[c] = __builtin_amdgcn_mfma_f32_16x16x32_bf16(a[t], b, acc[c], 0, 0, 0);
        }
    }

    #pragma unroll
    for (int c = 0; c < 3; c++) {
        int col = c * 16 + lrow;
        if (col < 40) {
            float bv = bop[col];
            #pragma unroll
            for (int r = 0; r < 4; r++) {
                int orow = row0 + lk * 4 + r;
                if (orow < nrows)
                    out[(size_t)orow * 40 + col] = acc[c][r] + bv;
            }
        }
    }
}

// ============================== launch =====================================

extern "C" void kernel_launch(void* const* d_in, const int* in_sizes, int n_in,
                              void* d_out, int out_size, void* d_ws, size_t ws_size,
                              hipStream_t stream)
{
    const float* x   = (const float*)d_in[0];
    const int*   src = (const int*)d_in[1];
    const int*   dst = (const int*)d_in[2];
    const float* ew  = (const float*)d_in[3];
    const float* Wr  = (const float*)d_in[4];
    const float* br  = (const float*)d_in[5];
    const float* W1  = (const float*)d_in[6];
    const float* b1  = (const float*)d_in[7];
    const float* W2  = (const float*)d_in[8];
    const float* b2  = (const float*)d_in[9];
    const float* W3  = (const float*)d_in[10];
    const float* b3  = (const float*)d_in[11];
    const float* Wop = (const float*)d_in[12];
    const float* bop = (const float*)d_in[13];
    float* out = (float*)d_out;

    const int n_nodes = in_sizes[0] / NF;   // 50000
    const int n_edges = in_sizes[1];        // 640000
    const size_t feat = (size_t)n_nodes * NF;

    // workspace layout
    u16* xb   = (u16*)d_ws;
    u16* hb   = xb + feat;
    u16* aggb = hb + feat;
    u16* resb = aggb + feat;
    u16* Wt   = resb + feat;                 // 4 * 128*128
    u16* Wtop = Wt + 4 * 16384;              // 48*128
    int* rowptr = (int*)(Wtop + 48 * 128);   // n+1 (counts -> rowptr)
    const int G1 = (n_nodes + 255) / 256;
    int* bsums  = rowptr + (n_nodes + 1);    // G1+1
    int* rank   = bsums + (G1 + 1);          // n_edges
    u32* ppairs = (u32*)(rank + n_edges);    // n_edges

    const int edge_grid = (n_edges + 255) / 256;
    const int gemm_grid = (n_nodes + 63) / 64;
    const int agg_grid  = (n_nodes * 16 + 255) / 256;
    const int castx_grid = ((int)feat / 4 + 255) / 256;

    // ---- CSR build (rank-based, packed) ----
    hipMemsetAsync(rowptr, 0, (size_t)(n_nodes + 1) * sizeof(int), stream);
    hist_rank<<<edge_grid, 256, 0, stream>>>(dst, rowptr, rank, n_edges);
    scan_pass1<<<G1, 256, 0, stream>>>(rowptr, bsums, n_nodes);
    scan_pass2<<<1, 256, 0, stream>>>(bsums, G1);
    scan_pass3<<<G1, 256, 0, stream>>>(rowptr, bsums, n_nodes, G1);
    fill_packed<<<edge_grid, 256, 0, stream>>>(src, dst, ew, rowptr, rank, ppairs, n_edges);

    // ---- casts ----
    cast_x_bf16<<<castx_grid, 256, 0, stream>>>(x, xb, (int)feat);
    prep_weights<<<(4 * 16384 + 48 * 128 + 255) / 256, 256, 0, stream>>>(
        Wr, W1, W2, W3, Wop, Wt, Wtop);

    // ---- res = x @ Wr + br ----
    gemm_mfma128<0, 0><<<gemm_grid, 256, 0, stream>>>(xb, Wt, br, nullptr, resb, n_nodes);

    // ---- 3 GCN layers (separate gather + GEMM) ----
    agg_gather_b<<<agg_grid, 256, 0, stream>>>(xb, rowptr, ppairs, aggb, n_nodes);
    gemm_mfma128<1, 0><<<gemm_grid, 256, 0, stream>>>(aggb, Wt + 16384, b1, nullptr, hb, n_nodes);

    agg_gather_b<<<agg_grid, 256, 0, stream>>>(hb, rowptr, ppairs, aggb, n_nodes);
    gemm_mfma128<1, 0><<<gemm_grid, 256, 0, stream>>>(aggb, Wt + 2 * 16384, b2, nullptr, hb, n_nodes);

    agg_gather_b<<<agg_grid, 256, 0, stream>>>(hb, rowptr, ppairs, aggb, n_nodes);
    gemm_mfma128<1, 1><<<gemm_grid, 256, 0, stream>>>(aggb, Wt + 3 * 16384, b3, resb, hb, n_nodes);

    // ---- output projection ----
    gemm_out40_mfma<<<gemm_grid, 256, 0, stream>>>(hb, Wtop, bop, out, n_nodes);
}